// Round 1
// baseline (1426.646 us; speedup 1.0000x reference)
//
#include <hip/hip_runtime.h>

#define N_NODES 100000
#define N_EDGES 1600000
#define IN_DIM  128
#define EDGE_DIM 16
#define HID     64
#define NGRAPH  2048
#define NEG_SLOPE 0.2f
#define NB ((N_NODES + 255) / 256)   // scan blocks = 391

// ---------------- CSR build ----------------
__global__ void k_indeg(const int* __restrict__ dst, int* __restrict__ cnt) {
    int e = blockIdx.x * blockDim.x + threadIdx.x;
    if (e < N_EDGES) atomicAdd(&cnt[dst[e]], 1);
}

__global__ void k_scan1(const int* __restrict__ cnt, int* __restrict__ rowstart,
                        int* __restrict__ bsum) {
    __shared__ int s[256];
    int t = threadIdx.x, b = blockIdx.x;
    int i = b * 256 + t;
    int v = (i < N_NODES) ? cnt[i] : 0;
    s[t] = v; __syncthreads();
    for (int off = 1; off < 256; off <<= 1) {
        int add = (t >= off) ? s[t - off] : 0;
        __syncthreads();
        s[t] += add;
        __syncthreads();
    }
    if (i < N_NODES) rowstart[i + 1] = s[t];
    if (t == 255) bsum[b] = s[255];
}

__global__ void k_scan2(int* bsum) {
    __shared__ int s[NB];
    int t = threadIdx.x;
    for (int i = t; i < NB; i += blockDim.x) s[i] = bsum[i];
    __syncthreads();
    if (t == 0) { int run = 0; for (int i = 0; i < NB; i++) { run += s[i]; s[i] = run; } }
    __syncthreads();
    for (int i = t; i < NB; i += blockDim.x) bsum[i] = s[i];
}

__global__ void k_scan3(int* rowstart, const int* __restrict__ bsum) {
    int t = threadIdx.x, b = blockIdx.x;
    int i = b * 256 + t;
    if (b == 0 && t == 0) rowstart[0] = 0;
    if (i < N_NODES && b > 0) rowstart[i + 1] += bsum[b - 1];
}

__global__ void k_scatter(const int* __restrict__ src, const int* __restrict__ dst,
                          const int* __restrict__ rowstart, int* cursor,
                          int* __restrict__ csr_eid, int* __restrict__ csr_src) {
    int e = blockIdx.x * blockDim.x + threadIdx.x;
    if (e >= N_EDGES) return;
    int d = dst[e];
    int pos = atomicAdd(&cursor[d], 1);
    int slot = rowstart[d] + pos;
    csr_eid[slot] = e;
    csr_src[slot] = src[e];
}

__global__ void k_dinv(const int* __restrict__ cnt, float* __restrict__ dinv) {
    int i = blockIdx.x * blockDim.x + threadIdx.x;
    if (i < N_NODES) dinv[i] = rsqrtf((float)(cnt[i] + 1));   // +1 self loop
}

// ---------------- GCN ----------------
// h0 = x @ W  (K=128). wave-per-row, W in LDS.
__global__ __launch_bounds__(256) void k_gemm_gcn(const float* __restrict__ x,
                                                  const float* __restrict__ W,
                                                  float* __restrict__ out) {
    __shared__ float Wl[IN_DIM * HID];
    for (int i = threadIdx.x; i < IN_DIM * HID; i += 256) Wl[i] = W[i];
    __syncthreads();
    int lane = threadIdx.x & 63;
    int wid  = (blockIdx.x * 256 + threadIdx.x) >> 6;
    int nw   = (gridDim.x * 256) >> 6;
    for (int r = wid; r < N_NODES; r += nw) {
        float x0 = x[r * IN_DIM + lane];
        float x1 = x[r * IN_DIM + 64 + lane];
        float acc = 0.f;
        #pragma unroll
        for (int k = 0; k < 64; k++) acc += __shfl(x0, k) * Wl[k * HID + lane];
        #pragma unroll
        for (int k = 0; k < 64; k++) acc += __shfl(x1, k) * Wl[(64 + k) * HID + lane];
        out[r * HID + lane] = acc;
    }
}

// out[n] = relu( sum_{e:(s->n)} h0[s]*dinv[s]*dinv[n] + h0[n]*dinv[n]^2 + b )
__global__ __launch_bounds__(256) void k_gcn_agg(const float* __restrict__ h0,
        const int* __restrict__ rowstart, const int* __restrict__ csr_src,
        const float* __restrict__ dinv, const float* __restrict__ b,
        float* __restrict__ out) {
    int lane = threadIdx.x & 63;
    int node = (blockIdx.x * 256 + threadIdx.x) >> 6;
    if (node >= N_NODES) return;
    float dn = dinv[node];
    float acc = h0[node * HID + lane] * dn * dn;
    int r0 = rowstart[node], r1 = rowstart[node + 1];
    for (int j = r0; j < r1; j++) {
        int s = csr_src[j];
        acc += h0[s * HID + lane] * (dinv[s] * dn);
    }
    float v = acc + b[lane];
    out[node * HID + lane] = v > 0.f ? v : 0.f;
}

// ---------------- shared GAT pieces ----------------
// mean incoming edge_attr per node (layer-invariant)
__global__ __launch_bounds__(256) void k_ea_mean(const float* __restrict__ ea,
        const int* __restrict__ rowstart, const int* __restrict__ csr_eid,
        float* __restrict__ ea_mean) {
    int lane = threadIdx.x & 63;
    int node = (blockIdx.x * 256 + threadIdx.x) >> 6;
    if (node >= N_NODES) return;
    int r0 = rowstart[node], r1 = rowstart[node + 1];
    int c = lane & 15, j4 = lane >> 4;            // 4 edges in flight per wave
    float sum = 0.f;
    for (int k = r0 + j4; k < r1; k += 4) {
        int e = csr_eid[k];
        sum += ea[e * EDGE_DIM + c];
    }
    sum += __shfl_xor(sum, 16);
    sum += __shfl_xor(sum, 32);
    int cnt = r1 - r0;
    if (lane < 16) ea_mean[node * EDGE_DIM + lane] = sum / (float)(cnt > 0 ? cnt : 1);
}

// hw = h @ W ; a_s[n] = hw[n]·att_s ; a_d[n] = hw[n]·att_d   (fused epilogue)
__global__ __launch_bounds__(256) void k_gemm_gat(const float* __restrict__ h,
        const float* __restrict__ W, const float* __restrict__ att_s,
        const float* __restrict__ att_d, float* __restrict__ hw,
        float* __restrict__ a_s, float* __restrict__ a_d) {
    __shared__ float Wl[HID * HID];
    for (int i = threadIdx.x; i < HID * HID; i += 256) Wl[i] = W[i];
    __syncthreads();
    int lane = threadIdx.x & 63;
    int wid  = (blockIdx.x * 256 + threadIdx.x) >> 6;
    int nw   = (gridDim.x * 256) >> 6;
    float ats = att_s[lane], atd = att_d[lane];
    for (int r = wid; r < N_NODES; r += nw) {
        float x0 = h[r * HID + lane];
        float acc = 0.f;
        #pragma unroll
        for (int k = 0; k < 64; k++) acc += __shfl(x0, k) * Wl[k * HID + lane];
        hw[r * HID + lane] = acc;
        float vs = acc * ats, vd = acc * atd;
        #pragma unroll
        for (int off = 32; off; off >>= 1) { vs += __shfl_xor(vs, off); vd += __shfl_xor(vd, off); }
        if (lane == 0) { a_s[r] = vs; a_d[r] = vd; }
    }
}

// a_e[e] = leaky( a_s[src] + a_d[dst] + edge_attr[e]·(We@att_e) )
__global__ __launch_bounds__(256) void k_edge_a(const float* __restrict__ ea,
        const int* __restrict__ src, const int* __restrict__ dst,
        const float* __restrict__ We, const float* __restrict__ att_e,
        const float* __restrict__ a_s, const float* __restrict__ a_d,
        float* __restrict__ a_e) {
    __shared__ float we[EDGE_DIM];
    if (threadIdx.x < EDGE_DIM) {
        float w = 0.f;
        for (int c = 0; c < HID; c++) w += We[threadIdx.x * HID + c] * att_e[c];
        we[threadIdx.x] = w;
    }
    __syncthreads();
    int e = blockIdx.x * blockDim.x + threadIdx.x;
    if (e >= N_EDGES) return;
    const float4* p = (const float4*)(ea + (size_t)e * EDGE_DIM);
    float4 v0 = p[0], v1 = p[1], v2 = p[2], v3 = p[3];
    float dotv = v0.x*we[0] + v0.y*we[1] + v0.z*we[2] + v0.w*we[3]
               + v1.x*we[4] + v1.y*we[5] + v1.z*we[6] + v1.w*we[7]
               + v2.x*we[8] + v2.y*we[9] + v2.z*we[10]+ v2.w*we[11]
               + v3.x*we[12]+ v3.y*we[13]+ v3.z*we[14]+ v3.w*we[15];
    float a = a_s[src[e]] + a_d[dst[e]] + dotv;
    a_e[e] = a > 0.f ? a : NEG_SLOPE * a;
}

// per-node: segment softmax over incoming edges (+ self loop) and aggregate hw rows
__global__ __launch_bounds__(256) void k_gat_agg(const float* __restrict__ hw,
        const int* __restrict__ rowstart, const int* __restrict__ csr_eid,
        const int* __restrict__ csr_src, const float* __restrict__ a_e,
        const float* __restrict__ a_s, const float* __restrict__ a_d,
        const float* __restrict__ ea_mean, const float* __restrict__ We,
        const float* __restrict__ att_e, const float* __restrict__ b,
        float* __restrict__ out) {
    __shared__ float we[EDGE_DIM];
    if (threadIdx.x < EDGE_DIM) {
        float w = 0.f;
        for (int c = 0; c < HID; c++) w += We[threadIdx.x * HID + c] * att_e[c];
        we[threadIdx.x] = w;
    }
    __syncthreads();
    int lane = threadIdx.x & 63;
    int node = (blockIdx.x * 256 + threadIdx.x) >> 6;
    if (node >= N_NODES) return;
    int r0 = rowstart[node], r1 = rowstart[node + 1];
    // self-loop attention logit (edge attr = mean of incoming)
    float v = (lane < EDGE_DIM) ? ea_mean[node * EDGE_DIM + lane] * we[lane] : 0.f;
    #pragma unroll
    for (int off = 32; off; off >>= 1) v += __shfl_xor(v, off);
    float al = a_s[node] + a_d[node] + v;
    al = al > 0.f ? al : NEG_SLOPE * al;
    // segment max (edges lane-parallel, then reduce)
    float m = al;
    for (int k = r0 + lane; k < r1; k += 64) m = fmaxf(m, a_e[csr_eid[k]]);
    #pragma unroll
    for (int off = 32; off; off >>= 1) m = fmaxf(m, __shfl_xor(m, off));
    // weighted aggregation; lane = feature column
    float wl  = __expf(al - m);
    float den = wl;
    float acc = wl * hw[node * HID + lane];
    for (int j = r0; j < r1; j++) {
        int e = csr_eid[j], s = csr_src[j];   // wave-uniform -> scalar loads
        float w = __expf(a_e[e] - m);
        den += w;
        acc += w * hw[s * HID + lane];
    }
    float o = acc / den + b[lane];
    out[node * HID + lane] = o > 0.f ? o : 0.f;
}

// ---------------- pool + FCs ----------------
__global__ void k_pool(const float* __restrict__ h, const int* __restrict__ batch,
                       float* __restrict__ g) {
    int idx = blockIdx.x * blockDim.x + threadIdx.x;
    if (idx >= N_NODES * HID) return;
    int n = idx >> 6, c = idx & 63;
    float v = h[idx];                       // v >= 0 (post-relu) -> int-bit max is valid
    atomicMax((int*)&g[batch[n] * HID + c], __float_as_int(v));
}

__global__ __launch_bounds__(256) void k_fc(const float* __restrict__ g,
        const float* __restrict__ W1, const float* __restrict__ b1,
        const float* __restrict__ W2, const float* __restrict__ b2,
        float* __restrict__ out) {
    __shared__ float W1l[HID * HID];
    __shared__ float W2l[HID * HID];
    for (int i = threadIdx.x; i < HID * HID; i += 256) { W1l[i] = W1[i]; W2l[i] = W2[i]; }
    __syncthreads();
    int lane = threadIdx.x & 63;
    int r = (blockIdx.x * 256 + threadIdx.x) >> 6;
    if (r >= NGRAPH) return;
    float x0 = g[r * HID + lane];
    float acc = b1[lane];
    #pragma unroll
    for (int k = 0; k < 64; k++) acc += __shfl(x0, k) * W1l[k * HID + lane];
    float t = acc > 0.f ? acc : 0.f;
    float acc2 = b2[lane];
    #pragma unroll
    for (int k = 0; k < 64; k++) acc2 += __shfl(t, k) * W2l[k * HID + lane];
    out[r * HID + lane] = acc2;
}

// ---------------- launch ----------------
extern "C" void kernel_launch(void* const* d_in, const int* in_sizes, int n_in,
                              void* d_out, int out_size, void* d_ws, size_t ws_size,
                              hipStream_t stream) {
    const float* x         = (const float*)d_in[0];
    const int*   edge_index= (const int*)d_in[1];
    const float* edge_attr = (const float*)d_in[2];
    const int*   batch     = (const int*)d_in[3];
    const float* W_gcn = (const float*)d_in[4];
    const float* b_gcn = (const float*)d_in[5];
    const float* W_gat1 = (const float*)d_in[6];
    const float* We_gat1= (const float*)d_in[7];
    const float* as_gat1= (const float*)d_in[8];
    const float* ad_gat1= (const float*)d_in[9];
    const float* ae_gat1= (const float*)d_in[10];
    const float* b_gat1 = (const float*)d_in[11];
    const float* W_gat2 = (const float*)d_in[12];
    const float* We_gat2= (const float*)d_in[13];
    const float* as_gat2= (const float*)d_in[14];
    const float* ad_gat2= (const float*)d_in[15];
    const float* ae_gat2= (const float*)d_in[16];
    const float* b_gat2 = (const float*)d_in[17];
    const float* W_fc1 = (const float*)d_in[18];
    const float* b_fc1 = (const float*)d_in[19];
    const float* W_fc2 = (const float*)d_in[20];
    const float* b_fc2 = (const float*)d_in[21];
    const int* src = edge_index;
    const int* dst = edge_index + N_EDGES;

    char* w = (char*)d_ws;
    auto alloc = [&](size_t bytes) -> char* {
        char* p = w; w += (bytes + 255) & ~(size_t)255; return p;
    };
    int*   cnt      = (int*)  alloc(N_NODES * 4);
    int*   rowstart = (int*)  alloc((N_NODES + 1) * 4);
    int*   cursor   = (int*)  alloc(N_NODES * 4);
    int*   csr_eid  = (int*)  alloc((size_t)N_EDGES * 4);
    int*   csr_src  = (int*)  alloc((size_t)N_EDGES * 4);
    float* dinv     = (float*)alloc(N_NODES * 4);
    float* a_s      = (float*)alloc(N_NODES * 4);
    float* a_d      = (float*)alloc(N_NODES * 4);
    float* a_e      = (float*)alloc((size_t)N_EDGES * 4);
    float* ea_mean  = (float*)alloc((size_t)N_NODES * EDGE_DIM * 4);
    float* bufA     = (float*)alloc((size_t)N_NODES * HID * 4);
    float* bufB     = (float*)alloc((size_t)N_NODES * HID * 4);
    int*   bsum     = (int*)  alloc(4096);
    float* g        = (float*)alloc((size_t)NGRAPH * HID * 4);

    hipMemsetAsync(cnt,    0, N_NODES * 4, stream);
    hipMemsetAsync(cursor, 0, N_NODES * 4, stream);
    hipMemsetAsync(g,      0, (size_t)NGRAPH * HID * 4, stream);

    // CSR build (shared by all three conv layers)
    k_indeg  <<<(N_EDGES + 255) / 256, 256, 0, stream>>>(dst, cnt);
    k_scan1  <<<NB, 256, 0, stream>>>(cnt, rowstart, bsum);
    k_scan2  <<<1, 512, 0, stream>>>(bsum);
    k_scan3  <<<NB, 256, 0, stream>>>(rowstart, bsum);
    k_scatter<<<(N_EDGES + 255) / 256, 256, 0, stream>>>(src, dst, rowstart, cursor, csr_eid, csr_src);
    k_dinv   <<<(N_NODES + 255) / 256, 256, 0, stream>>>(cnt, dinv);

    // GCN
    k_gemm_gcn<<<1024, 256, 0, stream>>>(x, W_gcn, bufB);
    k_gcn_agg <<<(N_NODES + 3) / 4, 256, 0, stream>>>(bufB, rowstart, csr_src, dinv, b_gcn, bufA);

    // ea_mean (layer-invariant)
    k_ea_mean <<<(N_NODES + 3) / 4, 256, 0, stream>>>(edge_attr, rowstart, csr_eid, ea_mean);

    // GAT 1
    k_gemm_gat<<<1024, 256, 0, stream>>>(bufA, W_gat1, as_gat1, ad_gat1, bufB, a_s, a_d);
    k_edge_a  <<<(N_EDGES + 255) / 256, 256, 0, stream>>>(edge_attr, src, dst, We_gat1, ae_gat1, a_s, a_d, a_e);
    k_gat_agg <<<(N_NODES + 3) / 4, 256, 0, stream>>>(bufB, rowstart, csr_eid, csr_src, a_e, a_s, a_d,
                                                      ea_mean, We_gat1, ae_gat1, b_gat1, bufA);
    // GAT 2
    k_gemm_gat<<<1024, 256, 0, stream>>>(bufA, W_gat2, as_gat2, ad_gat2, bufB, a_s, a_d);
    k_edge_a  <<<(N_EDGES + 255) / 256, 256, 0, stream>>>(edge_attr, src, dst, We_gat2, ae_gat2, a_s, a_d, a_e);
    k_gat_agg <<<(N_NODES + 3) / 4, 256, 0, stream>>>(bufB, rowstart, csr_eid, csr_src, a_e, a_s, a_d,
                                                      ea_mean, We_gat2, ae_gat2, b_gat2, bufA);

    // pool + FCs
    k_pool<<<(N_NODES * HID + 255) / 256, 256, 0, stream>>>(bufA, batch, g);
    k_fc  <<<(NGRAPH + 3) / 4, 256, 0, stream>>>(g, W_fc1, b_fc1, W_fc2, b_fc2, (float*)d_out);
}

// Round 3
// 994.739 us; speedup vs baseline: 1.4342x; 1.4342x over previous
//
#include <hip/hip_runtime.h>

#define N_NODES 100000
#define N_EDGES 1600000
#define IN_DIM  128
#define EDGE_DIM 16
#define HID     64
#define NGRAPH  2048
#define NEG_SLOPE 0.2f
#define NB ((N_NODES + 255) / 256)   // scan blocks = 391

__device__ __forceinline__ float bcastf(float v, int j) {
    return __int_as_float(__builtin_amdgcn_readlane(__float_as_int(v), j));
}

__device__ __forceinline__ int lower_bound_i(const int* __restrict__ a, int n, int key) {
    int lo = 0, hi = n;
    while (lo < hi) { int mid = (lo + hi) >> 1; if (a[mid] < key) lo = mid + 1; else hi = mid; }
    return lo;
}

// ---------------- CSR build ----------------
__global__ void k_indeg(const int* __restrict__ dst, int* __restrict__ cnt) {
    int e = blockIdx.x * blockDim.x + threadIdx.x;
    if (e < N_EDGES) atomicAdd(&cnt[dst[e]], 1);
}

__global__ void k_scan1(const int* __restrict__ cnt, int* __restrict__ rowstart,
                        int* __restrict__ bsum) {
    __shared__ int s[256];
    int t = threadIdx.x, b = blockIdx.x;
    int i = b * 256 + t;
    int v = (i < N_NODES) ? cnt[i] : 0;
    s[t] = v; __syncthreads();
    for (int off = 1; off < 256; off <<= 1) {
        int add = (t >= off) ? s[t - off] : 0;
        __syncthreads();
        s[t] += add;
        __syncthreads();
    }
    if (i < N_NODES) rowstart[i + 1] = s[t];
    if (t == 255) bsum[b] = s[255];
}

__global__ void k_scan2(int* bsum) {
    __shared__ int s[NB];
    int t = threadIdx.x;
    for (int i = t; i < NB; i += blockDim.x) s[i] = bsum[i];
    __syncthreads();
    if (t == 0) { int run = 0; for (int i = 0; i < NB; i++) { run += s[i]; s[i] = run; } }
    __syncthreads();
    for (int i = t; i < NB; i += blockDim.x) bsum[i] = s[i];
}

__global__ void k_scan3(int* rowstart, const int* __restrict__ bsum) {
    int t = threadIdx.x, b = blockIdx.x;
    int i = b * 256 + t;
    if (b == 0 && t == 0) rowstart[0] = 0;
    if (i < N_NODES && b > 0) rowstart[i + 1] += bsum[b - 1];
}

__global__ void k_scatter(const int* __restrict__ src, const int* __restrict__ dst,
                          const int* __restrict__ rowstart, int* cursor,
                          int2* __restrict__ csr_es) {
    int e = blockIdx.x * blockDim.x + threadIdx.x;
    if (e >= N_EDGES) return;
    int d = dst[e];
    int pos = atomicAdd(&cursor[d], 1);
    csr_es[rowstart[d] + pos] = make_int2(src[e], e);   // (src, eid)
}

__global__ void k_dinv(const int* __restrict__ cnt, float* __restrict__ dinv) {
    int i = blockIdx.x * blockDim.x + threadIdx.x;
    if (i < N_NODES) dinv[i] = rsqrtf((float)(cnt[i] + 1));   // +1 self loop
}

// ---------------- per-edge dots for both GAT layers (single ea pass) ----------
__global__ __launch_bounds__(256) void k_dot2(const float* __restrict__ ea,
        const float* __restrict__ We1, const float* __restrict__ ae1,
        const float* __restrict__ We2, const float* __restrict__ ae2,
        float* __restrict__ dot1, float* __restrict__ dot2) {
    __shared__ float w1[EDGE_DIM], w2[EDGE_DIM];
    if (threadIdx.x < EDGE_DIM) {
        float s1 = 0.f, s2 = 0.f;
        for (int c = 0; c < HID; c++) {
            s1 += We1[threadIdx.x * HID + c] * ae1[c];
            s2 += We2[threadIdx.x * HID + c] * ae2[c];
        }
        w1[threadIdx.x] = s1; w2[threadIdx.x] = s2;
    }
    __syncthreads();
    int e = blockIdx.x * blockDim.x + threadIdx.x;
    if (e >= N_EDGES) return;
    const float4* p = (const float4*)(ea + (size_t)e * EDGE_DIM);
    float4 v0 = p[0], v1 = p[1], v2 = p[2], v3 = p[3];
    float d1 = v0.x*w1[0] + v0.y*w1[1] + v0.z*w1[2] + v0.w*w1[3]
             + v1.x*w1[4] + v1.y*w1[5] + v1.z*w1[6] + v1.w*w1[7]
             + v2.x*w1[8] + v2.y*w1[9] + v2.z*w1[10]+ v2.w*w1[11]
             + v3.x*w1[12]+ v3.y*w1[13]+ v3.z*w1[14]+ v3.w*w1[15];
    float d2 = v0.x*w2[0] + v0.y*w2[1] + v0.z*w2[2] + v0.w*w2[3]
             + v1.x*w2[4] + v1.y*w2[5] + v1.z*w2[6] + v1.w*w2[7]
             + v2.x*w2[8] + v2.y*w2[9] + v2.z*w2[10]+ v2.w*w2[11]
             + v3.x*w2[12]+ v3.y*w2[13]+ v3.z*w2[14]+ v3.w*w2[15];
    dot1[e] = d1; dot2[e] = d2;
}

// ---------------- GCN ----------------
__global__ __launch_bounds__(256) void k_gemm_gcn(const float* __restrict__ x,
                                                  const float* __restrict__ W,
                                                  float* __restrict__ out) {
    __shared__ float Wl[IN_DIM * HID];
    for (int i = threadIdx.x; i < IN_DIM * HID; i += 256) Wl[i] = W[i];
    __syncthreads();
    int lane = threadIdx.x & 63;
    int wid  = (blockIdx.x * 256 + threadIdx.x) >> 6;
    int nw   = (gridDim.x * 256) >> 6;
    for (int r = wid; r < N_NODES; r += nw) {
        float x0 = x[r * IN_DIM + lane];
        float x1 = x[r * IN_DIM + 64 + lane];
        float acc = 0.f;
        #pragma unroll
        for (int k = 0; k < 64; k++) acc += __shfl(x0, k) * Wl[k * HID + lane];
        #pragma unroll
        for (int k = 0; k < 64; k++) acc += __shfl(x1, k) * Wl[(64 + k) * HID + lane];
        out[r * HID + lane] = acc;
    }
}

// out[n] = relu( sum_in h0[s]*dinv[s]*dinv[n] + h0[n]*dinv[n]^2 + b )
__global__ __launch_bounds__(256) void k_gcn_agg(const float* __restrict__ h0,
        const int* __restrict__ rowstart, const int2* __restrict__ csr_es,
        const float* __restrict__ dinv, const float* __restrict__ b,
        float* __restrict__ out) {
    int lane = threadIdx.x & 63;
    int node = (blockIdx.x * 256 + threadIdx.x) >> 6;
    if (node >= N_NODES) return;
    float dn = dinv[node];
    float acc = h0[node * HID + lane] * dn * dn;
    int r0 = rowstart[node], r1 = rowstart[node + 1];
    for (int base = r0; base < r1; base += 64) {
        int nloc = min(64, r1 - base);
        int s = node; float w = 0.f;
        if (lane < nloc) {
            s = csr_es[base + lane].x;
            w = dinv[s] * dn;
        }
        int d4 = nloc & ~3;
        for (int j = 0; j < d4; j += 4) {
            int s0 = __builtin_amdgcn_readlane(s, j);
            int s1 = __builtin_amdgcn_readlane(s, j + 1);
            int s2 = __builtin_amdgcn_readlane(s, j + 2);
            int s3 = __builtin_amdgcn_readlane(s, j + 3);
            float w0 = bcastf(w, j),     w1 = bcastf(w, j + 1);
            float w2 = bcastf(w, j + 2), w3 = bcastf(w, j + 3);
            float h0v = h0[s0 * HID + lane];
            float h1v = h0[s1 * HID + lane];
            float h2v = h0[s2 * HID + lane];
            float h3v = h0[s3 * HID + lane];
            acc = fmaf(w0, h0v, acc); acc = fmaf(w1, h1v, acc);
            acc = fmaf(w2, h2v, acc); acc = fmaf(w3, h3v, acc);
        }
        for (int j = d4; j < nloc; j++) {
            int sj = __builtin_amdgcn_readlane(s, j);
            float wj = bcastf(w, j);
            acc = fmaf(wj, h0[sj * HID + lane], acc);
        }
    }
    float v = acc + b[lane];
    out[node * HID + lane] = v > 0.f ? v : 0.f;
}

// hw = h @ W ; a_s[n] = hw[n]·att_s ; a_d[n] = hw[n]·att_d
__global__ __launch_bounds__(256) void k_gemm_gat(const float* __restrict__ h,
        const float* __restrict__ W, const float* __restrict__ att_s,
        const float* __restrict__ att_d, float* __restrict__ hw,
        float* __restrict__ a_s, float* __restrict__ a_d) {
    __shared__ float Wl[HID * HID];
    for (int i = threadIdx.x; i < HID * HID; i += 256) Wl[i] = W[i];
    __syncthreads();
    int lane = threadIdx.x & 63;
    int wid  = (blockIdx.x * 256 + threadIdx.x) >> 6;
    int nw   = (gridDim.x * 256) >> 6;
    float ats = att_s[lane], atd = att_d[lane];
    for (int r = wid; r < N_NODES; r += nw) {
        float x0 = h[r * HID + lane];
        float acc = 0.f;
        #pragma unroll
        for (int k = 0; k < 64; k++) acc += __shfl(x0, k) * Wl[k * HID + lane];
        hw[r * HID + lane] = acc;
        float vs = acc * ats, vd = acc * atd;
        #pragma unroll
        for (int off = 32; off; off >>= 1) { vs += __shfl_xor(vs, off); vd += __shfl_xor(vd, off); }
        if (lane == 0) { a_s[r] = vs; a_d[r] = vd; }
    }
}

// fused: edge logits (from dot) + segment softmax + aggregation + bias + relu
__global__ __launch_bounds__(256) void k_gat_agg(const float* __restrict__ hw,
        const int* __restrict__ rowstart, const int2* __restrict__ csr_es,
        const float* __restrict__ dotv, const float* __restrict__ a_s,
        const float* __restrict__ a_d, const float* __restrict__ b,
        float* __restrict__ out) {
    int lane = threadIdx.x & 63;
    int node = (blockIdx.x * 256 + threadIdx.x) >> 6;
    if (node >= N_NODES) return;
    int r0 = rowstart[node], r1 = rowstart[node + 1];
    int deg = r1 - r0;
    float adn = a_d[node];
    float asn = a_s[node];
    float bias = b[lane];
    float self_hw = hw[node * HID + lane];
    float acc, den;

    if (deg <= 64) {
        // ---- fast path: all edges lane-parallel ----
        int s = node; float dt = 0.f, ae = -3.0e38f;
        if (lane < deg) {
            int2 es = csr_es[r0 + lane];
            s = es.x;
            dt = dotv[es.y];
            float t = a_s[s] + adn + dt;
            ae = t > 0.f ? t : NEG_SLOPE * t;
        }
        float sdt = dt;                       // dt==0 on inactive lanes
        float m = ae;
        #pragma unroll
        for (int off = 32; off; off >>= 1) {
            sdt += __shfl_xor(sdt, off);
            m = fmaxf(m, __shfl_xor(m, off));
        }
        float t = asn + adn + sdt / (float)(deg > 0 ? deg : 1);   // self logit (mean dot)
        float al = t > 0.f ? t : NEG_SLOPE * t;
        m = fmaxf(m, al);
        float w = (lane < deg) ? __expf(ae - m) : 0.f;
        den = w;
        #pragma unroll
        for (int off = 32; off; off >>= 1) den += __shfl_xor(den, off);
        float wl = __expf(al - m);
        den += wl;
        acc = wl * self_hw;
        int d4 = deg & ~3;
        for (int j = 0; j < d4; j += 4) {
            int s0 = __builtin_amdgcn_readlane(s, j);
            int s1 = __builtin_amdgcn_readlane(s, j + 1);
            int s2 = __builtin_amdgcn_readlane(s, j + 2);
            int s3 = __builtin_amdgcn_readlane(s, j + 3);
            float w0 = bcastf(w, j),     w1 = bcastf(w, j + 1);
            float w2 = bcastf(w, j + 2), w3 = bcastf(w, j + 3);
            float h0v = hw[s0 * HID + lane];
            float h1v = hw[s1 * HID + lane];
            float h2v = hw[s2 * HID + lane];
            float h3v = hw[s3 * HID + lane];
            acc = fmaf(w0, h0v, acc); acc = fmaf(w1, h1v, acc);
            acc = fmaf(w2, h2v, acc); acc = fmaf(w3, h3v, acc);
        }
        for (int j = d4; j < deg; j++) {
            int sj = __builtin_amdgcn_readlane(s, j);
            float wj = bcastf(w, j);
            acc = fmaf(wj, hw[sj * HID + lane], acc);
        }
    } else {
        // ---- slow path (deg > 64, rare for E/N=16) ----
        float sdt = 0.f, mE = -3.0e38f;
        for (int k = r0 + lane; k < r1; k += 64) {
            int2 es = csr_es[k];
            float dt = dotv[es.y];
            sdt += dt;
            float t2 = a_s[es.x] + adn + dt;
            t2 = t2 > 0.f ? t2 : NEG_SLOPE * t2;
            mE = fmaxf(mE, t2);
        }
        #pragma unroll
        for (int off = 32; off; off >>= 1) {
            sdt += __shfl_xor(sdt, off);
            mE = fmaxf(mE, __shfl_xor(mE, off));
        }
        float t = asn + adn + sdt / (float)deg;
        float al = t > 0.f ? t : NEG_SLOPE * t;
        float m = fmaxf(mE, al);
        float wl = __expf(al - m);
        den = wl;
        acc = wl * self_hw;
        for (int base = r0; base < r1; base += 64) {
            int nloc = min(64, r1 - base);
            int s = node; float w = 0.f;
            if (lane < nloc) {
                int2 es = csr_es[base + lane];
                s = es.x;
                float dt = dotv[es.y];
                float t2 = a_s[s] + adn + dt;
                t2 = t2 > 0.f ? t2 : NEG_SLOPE * t2;
                w = __expf(t2 - m);
            }
            float dsum = w;
            #pragma unroll
            for (int off = 32; off; off >>= 1) dsum += __shfl_xor(dsum, off);
            den += dsum;
            for (int j = 0; j < nloc; j++) {
                int sj = __builtin_amdgcn_readlane(s, j);
                float wj = bcastf(w, j);
                acc = fmaf(wj, hw[sj * HID + lane], acc);
            }
        }
    }
    float o = acc / den + bias;
    out[node * HID + lane] = o > 0.f ? o : 0.f;
}

// ---------------- fused pool (batch is sorted -> binary search) + both FCs ----
__global__ __launch_bounds__(256) void k_pool_fc(const float* __restrict__ h,
        const int* __restrict__ batch,
        const float* __restrict__ W1, const float* __restrict__ b1,
        const float* __restrict__ W2, const float* __restrict__ b2,
        float* __restrict__ out) {
    __shared__ float W1l[HID * HID];
    __shared__ float W2l[HID * HID];
    for (int i = threadIdx.x; i < HID * HID; i += 256) { W1l[i] = W1[i]; W2l[i] = W2[i]; }
    __syncthreads();
    int lane = threadIdx.x & 63;
    int gph  = (blockIdx.x * 256 + threadIdx.x) >> 6;
    if (gph >= NGRAPH) return;
    int start = lower_bound_i(batch, N_NODES, gph);       // wave-uniform scalar search
    int end   = lower_bound_i(batch, N_NODES, gph + 1);
    float acc = 0.f;                                      // h >= 0 post-relu
    for (int n = start; n < end; n++) acc = fmaxf(acc, h[n * HID + lane]);
    float v = b1[lane];
    #pragma unroll
    for (int k = 0; k < 64; k++) v += __shfl(acc, k) * W1l[k * HID + lane];
    float t = v > 0.f ? v : 0.f;
    float v2 = b2[lane];
    #pragma unroll
    for (int k = 0; k < 64; k++) v2 += __shfl(t, k) * W2l[k * HID + lane];
    out[gph * HID + lane] = v2;
}

// ---------------- launch ----------------
extern "C" void kernel_launch(void* const* d_in, const int* in_sizes, int n_in,
                              void* d_out, int out_size, void* d_ws, size_t ws_size,
                              hipStream_t stream) {
    const float* x         = (const float*)d_in[0];
    const int*   edge_index= (const int*)d_in[1];
    const float* edge_attr = (const float*)d_in[2];
    const int*   batch     = (const int*)d_in[3];
    const float* W_gcn = (const float*)d_in[4];
    const float* b_gcn = (const float*)d_in[5];
    const float* W_gat1 = (const float*)d_in[6];
    const float* We_gat1= (const float*)d_in[7];
    const float* as_gat1= (const float*)d_in[8];
    const float* ad_gat1= (const float*)d_in[9];
    const float* ae_gat1= (const float*)d_in[10];
    const float* b_gat1 = (const float*)d_in[11];
    const float* W_gat2 = (const float*)d_in[12];
    const float* We_gat2= (const float*)d_in[13];
    const float* as_gat2= (const float*)d_in[14];
    const float* ad_gat2= (const float*)d_in[15];
    const float* ae_gat2= (const float*)d_in[16];
    const float* b_gat2 = (const float*)d_in[17];
    const float* W_fc1 = (const float*)d_in[18];
    const float* b_fc1 = (const float*)d_in[19];
    const float* W_fc2 = (const float*)d_in[20];
    const float* b_fc2 = (const float*)d_in[21];
    const int* src = edge_index;
    const int* dst = edge_index + N_EDGES;

    char* w = (char*)d_ws;
    auto alloc = [&](size_t bytes) -> char* {
        char* p = w; w += (bytes + 255) & ~(size_t)255; return p;
    };
    int*   cnt      = (int*)  alloc(N_NODES * 4);
    int*   rowstart = (int*)  alloc((N_NODES + 1) * 4);
    int*   cursor   = (int*)  alloc(N_NODES * 4);
    int2*  csr_es   = (int2*) alloc((size_t)N_EDGES * 8);
    float* dinv     = (float*)alloc(N_NODES * 4);
    float* a_s      = (float*)alloc(N_NODES * 4);
    float* a_d      = (float*)alloc(N_NODES * 4);
    float* dot1     = (float*)alloc((size_t)N_EDGES * 4);
    float* dot2     = (float*)alloc((size_t)N_EDGES * 4);
    float* bufA     = (float*)alloc((size_t)N_NODES * HID * 4);
    float* bufB     = (float*)alloc((size_t)N_NODES * HID * 4);
    int*   bsum     = (int*)  alloc(4096);

    hipMemsetAsync(cnt,    0, N_NODES * 4, stream);
    hipMemsetAsync(cursor, 0, N_NODES * 4, stream);

    // CSR build (shared by all three conv layers)
    k_indeg  <<<(N_EDGES + 255) / 256, 256, 0, stream>>>(dst, cnt);
    k_scan1  <<<NB, 256, 0, stream>>>(cnt, rowstart, bsum);
    k_scan2  <<<1, 512, 0, stream>>>(bsum);
    k_scan3  <<<NB, 256, 0, stream>>>(rowstart, bsum);
    k_scatter<<<(N_EDGES + 255) / 256, 256, 0, stream>>>(src, dst, rowstart, cursor, csr_es);
    k_dinv   <<<(N_NODES + 255) / 256, 256, 0, stream>>>(cnt, dinv);

    // per-edge attention dots for both GAT layers (one streaming pass over ea)
    k_dot2<<<(N_EDGES + 255) / 256, 256, 0, stream>>>(edge_attr, We_gat1, ae_gat1,
                                                      We_gat2, ae_gat2, dot1, dot2);

    // GCN
    k_gemm_gcn<<<1024, 256, 0, stream>>>(x, W_gcn, bufB);
    k_gcn_agg <<<(N_NODES + 3) / 4, 256, 0, stream>>>(bufB, rowstart, csr_es, dinv, b_gcn, bufA);

    // GAT 1
    k_gemm_gat<<<1024, 256, 0, stream>>>(bufA, W_gat1, as_gat1, ad_gat1, bufB, a_s, a_d);
    k_gat_agg <<<(N_NODES + 3) / 4, 256, 0, stream>>>(bufB, rowstart, csr_es, dot1, a_s, a_d, b_gat1, bufA);

    // GAT 2
    k_gemm_gat<<<1024, 256, 0, stream>>>(bufA, W_gat2, as_gat2, ad_gat2, bufB, a_s, a_d);
    k_gat_agg <<<(N_NODES + 3) / 4, 256, 0, stream>>>(bufB, rowstart, csr_es, dot2, a_s, a_d, b_gat2, bufA);

    // fused pool + FCs (batch sorted -> binary search per graph, no atomics)
    k_pool_fc<<<(NGRAPH + 3) / 4, 256, 0, stream>>>(bufA, batch, W_fc1, b_fc1, W_fc2, b_fc2, (float*)d_out);
}

// Round 4
// 768.124 us; speedup vs baseline: 1.8573x; 1.2950x over previous
//
#include <hip/hip_runtime.h>

#define N_NODES 100000
#define N_EDGES 1600000
#define IN_DIM  128
#define EDGE_DIM 16
#define HID     64
#define NGRAPH  2048
#define NEG_SLOPE 0.2f
#define NB ((N_NODES + 255) / 256)   // scan blocks = 391

__device__ __forceinline__ float bcastf(float v, int j) {
    return __int_as_float(__builtin_amdgcn_readlane(__float_as_int(v), j));
}

__device__ __forceinline__ int lower_bound_i(const int* __restrict__ a, int n, int key) {
    int lo = 0, hi = n;
    while (lo < hi) { int mid = (lo + hi) >> 1; if (a[mid] < key) lo = mid + 1; else hi = mid; }
    return lo;
}

// ---------------- CSR build ----------------
__global__ void k_indeg(const int* __restrict__ dst, int* __restrict__ cnt) {
    int e = blockIdx.x * blockDim.x + threadIdx.x;
    if (e < N_EDGES) atomicAdd(&cnt[dst[e]], 1);
}

__global__ void k_scan1(const int* __restrict__ cnt, int* __restrict__ rowstart,
                        int* __restrict__ bsum) {
    __shared__ int s[256];
    int t = threadIdx.x, b = blockIdx.x;
    int i = b * 256 + t;
    int v = (i < N_NODES) ? cnt[i] : 0;
    s[t] = v; __syncthreads();
    for (int off = 1; off < 256; off <<= 1) {
        int add = (t >= off) ? s[t - off] : 0;
        __syncthreads();
        s[t] += add;
        __syncthreads();
    }
    if (i < N_NODES) rowstart[i + 1] = s[t];
    if (t == 255) bsum[b] = s[255];
}

__global__ void k_scan2(int* bsum) {
    __shared__ int s[NB];
    int t = threadIdx.x;
    for (int i = t; i < NB; i += blockDim.x) s[i] = bsum[i];
    __syncthreads();
    if (t == 0) { int run = 0; for (int i = 0; i < NB; i++) { run += s[i]; s[i] = run; } }
    __syncthreads();
    for (int i = t; i < NB; i += blockDim.x) bsum[i] = s[i];
}

__global__ void k_scan3(int* rowstart, const int* __restrict__ bsum) {
    int t = threadIdx.x, b = blockIdx.x;
    int i = b * 256 + t;
    if (b == 0 && t == 0) rowstart[0] = 0;
    if (i < N_NODES && b > 0) rowstart[i + 1] += bsum[b - 1];
}

__global__ void k_scatter(const int* __restrict__ src, const int* __restrict__ dst,
                          const int* __restrict__ rowstart, int* cursor,
                          int2* __restrict__ csr_es) {
    int e = blockIdx.x * blockDim.x + threadIdx.x;
    if (e >= N_EDGES) return;
    int d = dst[e];
    int pos = atomicAdd(&cursor[d], 1);
    csr_es[rowstart[d] + pos] = make_int2(src[e], e);   // (src, eid)
}

__global__ void k_dinv(const int* __restrict__ cnt, float* __restrict__ dinv) {
    int i = blockIdx.x * blockDim.x + threadIdx.x;
    if (i < N_NODES) dinv[i] = rsqrtf((float)(cnt[i] + 1));   // +1 self loop
}

// ---------------- per-edge dots for both GAT layers (single ea pass) ----------
__global__ __launch_bounds__(256) void k_dot2(const float* __restrict__ ea,
        const float* __restrict__ We1, const float* __restrict__ ae1,
        const float* __restrict__ We2, const float* __restrict__ ae2,
        float* __restrict__ dot1, float* __restrict__ dot2) {
    __shared__ float w1[EDGE_DIM], w2[EDGE_DIM];
    if (threadIdx.x < EDGE_DIM) {
        float s1 = 0.f, s2 = 0.f;
        for (int c = 0; c < HID; c++) {
            s1 += We1[threadIdx.x * HID + c] * ae1[c];
            s2 += We2[threadIdx.x * HID + c] * ae2[c];
        }
        w1[threadIdx.x] = s1; w2[threadIdx.x] = s2;
    }
    __syncthreads();
    int e = blockIdx.x * blockDim.x + threadIdx.x;
    if (e >= N_EDGES) return;
    const float4* p = (const float4*)(ea + (size_t)e * EDGE_DIM);
    float4 v0 = p[0], v1 = p[1], v2 = p[2], v3 = p[3];
    float d1 = v0.x*w1[0] + v0.y*w1[1] + v0.z*w1[2] + v0.w*w1[3]
             + v1.x*w1[4] + v1.y*w1[5] + v1.z*w1[6] + v1.w*w1[7]
             + v2.x*w1[8] + v2.y*w1[9] + v2.z*w1[10]+ v2.w*w1[11]
             + v3.x*w1[12]+ v3.y*w1[13]+ v3.z*w1[14]+ v3.w*w1[15];
    float d2 = v0.x*w2[0] + v0.y*w2[1] + v0.z*w2[2] + v0.w*w2[3]
             + v1.x*w2[4] + v1.y*w2[5] + v1.z*w2[6] + v1.w*w2[7]
             + v2.x*w2[8] + v2.y*w2[9] + v2.z*w2[10]+ v2.w*w2[11]
             + v3.x*w2[12]+ v3.y*w2[13]+ v3.z*w2[14]+ v3.w*w2[15];
    dot1[e] = d1; dot2[e] = d2;
}

// ---------------- GCN gemm: W columns in VGPRs, readlane broadcast (no LDS) --
__global__ __launch_bounds__(256) void k_gemm_gcn(const float* __restrict__ x,
                                                  const float* __restrict__ W,
                                                  float* __restrict__ out) {
    int lane = threadIdx.x & 63;
    int wid  = (blockIdx.x * 256 + threadIdx.x) >> 6;
    int nw   = (gridDim.x * 256) >> 6;
    float Wr[IN_DIM];                       // lane's W column, 128 VGPRs
    #pragma unroll
    for (int k = 0; k < IN_DIM; k++) Wr[k] = W[k * HID + lane];
    for (int r = wid; r < N_NODES; r += nw) {
        const float* xr = x + (size_t)r * IN_DIM;
        float x0 = xr[lane], x1 = xr[64 + lane];
        float a0 = 0.f, a1 = 0.f, a2 = 0.f, a3 = 0.f;
        #pragma unroll
        for (int k = 0; k < 64; k += 4) {
            a0 = fmaf(bcastf(x0, k),     Wr[k],     a0);
            a1 = fmaf(bcastf(x0, k + 1), Wr[k + 1], a1);
            a2 = fmaf(bcastf(x0, k + 2), Wr[k + 2], a2);
            a3 = fmaf(bcastf(x0, k + 3), Wr[k + 3], a3);
        }
        #pragma unroll
        for (int k = 0; k < 64; k += 4) {
            a0 = fmaf(bcastf(x1, k),     Wr[64 + k],     a0);
            a1 = fmaf(bcastf(x1, k + 1), Wr[64 + k + 1], a1);
            a2 = fmaf(bcastf(x1, k + 2), Wr[64 + k + 2], a2);
            a3 = fmaf(bcastf(x1, k + 3), Wr[64 + k + 3], a3);
        }
        out[(size_t)r * HID + lane] = (a0 + a1) + (a2 + a3);
    }
}

// out[n] = relu( sum_in h0[s]*dinv[s]*dinv[n] + h0[n]*dinv[n]^2 + b )
__global__ __launch_bounds__(256) void k_gcn_agg(const float* __restrict__ h0,
        const int* __restrict__ rowstart, const int2* __restrict__ csr_es,
        const float* __restrict__ dinv, const float* __restrict__ b,
        float* __restrict__ out) {
    int lane = threadIdx.x & 63;
    int node = (blockIdx.x * 256 + threadIdx.x) >> 6;
    if (node >= N_NODES) return;
    float dn = dinv[node];
    float acc = h0[node * HID + lane] * dn * dn;
    int r0 = rowstart[node], r1 = rowstart[node + 1];
    for (int base = r0; base < r1; base += 64) {
        int nloc = min(64, r1 - base);
        int s = node; float w = 0.f;
        if (lane < nloc) {
            s = csr_es[base + lane].x;
            w = dinv[s] * dn;
        }
        int d4 = nloc & ~3;
        for (int j = 0; j < d4; j += 4) {
            int s0 = __builtin_amdgcn_readlane(s, j);
            int s1 = __builtin_amdgcn_readlane(s, j + 1);
            int s2 = __builtin_amdgcn_readlane(s, j + 2);
            int s3 = __builtin_amdgcn_readlane(s, j + 3);
            float w0 = bcastf(w, j),     w1 = bcastf(w, j + 1);
            float w2 = bcastf(w, j + 2), w3 = bcastf(w, j + 3);
            float h0v = h0[s0 * HID + lane];
            float h1v = h0[s1 * HID + lane];
            float h2v = h0[s2 * HID + lane];
            float h3v = h0[s3 * HID + lane];
            acc = fmaf(w0, h0v, acc); acc = fmaf(w1, h1v, acc);
            acc = fmaf(w2, h2v, acc); acc = fmaf(w3, h3v, acc);
        }
        for (int j = d4; j < nloc; j++) {
            int sj = __builtin_amdgcn_readlane(s, j);
            float wj = bcastf(w, j);
            acc = fmaf(wj, h0[sj * HID + lane], acc);
        }
    }
    float v = acc + b[lane];
    out[node * HID + lane] = v > 0.f ? v : 0.f;
}

// hw = h @ W ; a_s = hw·att_s ; a_d = hw·att_d  (W column in VGPRs, no LDS gemm)
__global__ __launch_bounds__(256) void k_gemm_gat(const float* __restrict__ h,
        const float* __restrict__ W, const float* __restrict__ att_s,
        const float* __restrict__ att_d, float* __restrict__ hw,
        float* __restrict__ a_s, float* __restrict__ a_d) {
    int lane = threadIdx.x & 63;
    int wid  = (blockIdx.x * 256 + threadIdx.x) >> 6;
    int nw   = (gridDim.x * 256) >> 6;
    float Wr[HID];                          // lane's W column, 64 VGPRs
    #pragma unroll
    for (int k = 0; k < HID; k++) Wr[k] = W[k * HID + lane];
    float ats = att_s[lane], atd = att_d[lane];
    for (int r = wid; r < N_NODES; r += nw) {
        float x0 = h[(size_t)r * HID + lane];
        float a0 = 0.f, a1 = 0.f, a2 = 0.f, a3 = 0.f;
        #pragma unroll
        for (int k = 0; k < 64; k += 4) {
            a0 = fmaf(bcastf(x0, k),     Wr[k],     a0);
            a1 = fmaf(bcastf(x0, k + 1), Wr[k + 1], a1);
            a2 = fmaf(bcastf(x0, k + 2), Wr[k + 2], a2);
            a3 = fmaf(bcastf(x0, k + 3), Wr[k + 3], a3);
        }
        float acc = (a0 + a1) + (a2 + a3);
        hw[(size_t)r * HID + lane] = acc;
        float vs = acc * ats, vd = acc * atd;
        #pragma unroll
        for (int off = 32; off; off >>= 1) { vs += __shfl_xor(vs, off); vd += __shfl_xor(vd, off); }
        if (lane == 0) { a_s[r] = vs; a_d[r] = vd; }
    }
}

// fused: edge logits (from dot) + segment softmax + aggregation + bias + relu
__global__ __launch_bounds__(256) void k_gat_agg(const float* __restrict__ hw,
        const int* __restrict__ rowstart, const int2* __restrict__ csr_es,
        const float* __restrict__ dotv, const float* __restrict__ a_s,
        const float* __restrict__ a_d, const float* __restrict__ b,
        float* __restrict__ out) {
    int lane = threadIdx.x & 63;
    int node = (blockIdx.x * 256 + threadIdx.x) >> 6;
    if (node >= N_NODES) return;
    int r0 = rowstart[node], r1 = rowstart[node + 1];
    int deg = r1 - r0;
    float adn = a_d[node];
    float asn = a_s[node];
    float bias = b[lane];
    float self_hw = hw[node * HID + lane];
    float acc, den;

    if (deg <= 64) {
        // ---- fast path: all edges lane-parallel ----
        int s = node; float dt = 0.f, ae = -3.0e38f;
        if (lane < deg) {
            int2 es = csr_es[r0 + lane];
            s = es.x;
            dt = dotv[es.y];
            float t = a_s[s] + adn + dt;
            ae = t > 0.f ? t : NEG_SLOPE * t;
        }
        float sdt = dt;                       // dt==0 on inactive lanes
        float m = ae;
        #pragma unroll
        for (int off = 32; off; off >>= 1) {
            sdt += __shfl_xor(sdt, off);
            m = fmaxf(m, __shfl_xor(m, off));
        }
        float t = asn + adn + sdt / (float)(deg > 0 ? deg : 1);   // self logit (mean dot)
        float al = t > 0.f ? t : NEG_SLOPE * t;
        m = fmaxf(m, al);
        float w = (lane < deg) ? __expf(ae - m) : 0.f;
        den = w;
        #pragma unroll
        for (int off = 32; off; off >>= 1) den += __shfl_xor(den, off);
        float wl = __expf(al - m);
        den += wl;
        acc = wl * self_hw;
        int d4 = deg & ~3;
        for (int j = 0; j < d4; j += 4) {
            int s0 = __builtin_amdgcn_readlane(s, j);
            int s1 = __builtin_amdgcn_readlane(s, j + 1);
            int s2 = __builtin_amdgcn_readlane(s, j + 2);
            int s3 = __builtin_amdgcn_readlane(s, j + 3);
            float w0 = bcastf(w, j),     w1 = bcastf(w, j + 1);
            float w2 = bcastf(w, j + 2), w3 = bcastf(w, j + 3);
            float h0v = hw[s0 * HID + lane];
            float h1v = hw[s1 * HID + lane];
            float h2v = hw[s2 * HID + lane];
            float h3v = hw[s3 * HID + lane];
            acc = fmaf(w0, h0v, acc); acc = fmaf(w1, h1v, acc);
            acc = fmaf(w2, h2v, acc); acc = fmaf(w3, h3v, acc);
        }
        for (int j = d4; j < deg; j++) {
            int sj = __builtin_amdgcn_readlane(s, j);
            float wj = bcastf(w, j);
            acc = fmaf(wj, hw[sj * HID + lane], acc);
        }
    } else {
        // ---- slow path (deg > 64, rare for E/N=16) ----
        float sdt = 0.f, mE = -3.0e38f;
        for (int k = r0 + lane; k < r1; k += 64) {
            int2 es = csr_es[k];
            float dt = dotv[es.y];
            sdt += dt;
            float t2 = a_s[es.x] + adn + dt;
            t2 = t2 > 0.f ? t2 : NEG_SLOPE * t2;
            mE = fmaxf(mE, t2);
        }
        #pragma unroll
        for (int off = 32; off; off >>= 1) {
            sdt += __shfl_xor(sdt, off);
            mE = fmaxf(mE, __shfl_xor(mE, off));
        }
        float t = asn + adn + sdt / (float)deg;
        float al = t > 0.f ? t : NEG_SLOPE * t;
        float m = fmaxf(mE, al);
        float wl = __expf(al - m);
        den = wl;
        acc = wl * self_hw;
        for (int base = r0; base < r1; base += 64) {
            int nloc = min(64, r1 - base);
            int s = node; float w = 0.f;
            if (lane < nloc) {
                int2 es = csr_es[base + lane];
                s = es.x;
                float dt = dotv[es.y];
                float t2 = a_s[s] + adn + dt;
                t2 = t2 > 0.f ? t2 : NEG_SLOPE * t2;
                w = __expf(t2 - m);
            }
            float dsum = w;
            #pragma unroll
            for (int off = 32; off; off >>= 1) dsum += __shfl_xor(dsum, off);
            den += dsum;
            for (int j = 0; j < nloc; j++) {
                int sj = __builtin_amdgcn_readlane(s, j);
                float wj = bcastf(w, j);
                acc = fmaf(wj, hw[sj * HID + lane], acc);
            }
        }
    }
    float o = acc / den + bias;
    out[node * HID + lane] = o > 0.f ? o : 0.f;
}

// ---------------- fused pool (batch is sorted -> binary search) + both FCs ----
__global__ __launch_bounds__(256) void k_pool_fc(const float* __restrict__ h,
        const int* __restrict__ batch,
        const float* __restrict__ W1, const float* __restrict__ b1,
        const float* __restrict__ W2, const float* __restrict__ b2,
        float* __restrict__ out) {
    __shared__ float W1l[HID * HID];
    __shared__ float W2l[HID * HID];
    for (int i = threadIdx.x; i < HID * HID; i += 256) { W1l[i] = W1[i]; W2l[i] = W2[i]; }
    __syncthreads();
    int lane = threadIdx.x & 63;
    int gph  = (blockIdx.x * 256 + threadIdx.x) >> 6;
    if (gph >= NGRAPH) return;
    int start = lower_bound_i(batch, N_NODES, gph);       // wave-uniform scalar search
    int end   = lower_bound_i(batch, N_NODES, gph + 1);
    float acc = 0.f;                                      // h >= 0 post-relu
    for (int n = start; n < end; n++) acc = fmaxf(acc, h[n * HID + lane]);
    float v = b1[lane];
    #pragma unroll
    for (int k = 0; k < 64; k++) v += __shfl(acc, k) * W1l[k * HID + lane];
    float t = v > 0.f ? v : 0.f;
    float v2 = b2[lane];
    #pragma unroll
    for (int k = 0; k < 64; k++) v2 += __shfl(t, k) * W2l[k * HID + lane];
    out[gph * HID + lane] = v2;
}

// ---------------- launch ----------------
extern "C" void kernel_launch(void* const* d_in, const int* in_sizes, int n_in,
                              void* d_out, int out_size, void* d_ws, size_t ws_size,
                              hipStream_t stream) {
    const float* x         = (const float*)d_in[0];
    const int*   edge_index= (const int*)d_in[1];
    const float* edge_attr = (const float*)d_in[2];
    const int*   batch     = (const int*)d_in[3];
    const float* W_gcn = (const float*)d_in[4];
    const float* b_gcn = (const float*)d_in[5];
    const float* W_gat1 = (const float*)d_in[6];
    const float* We_gat1= (const float*)d_in[7];
    const float* as_gat1= (const float*)d_in[8];
    const float* ad_gat1= (const float*)d_in[9];
    const float* ae_gat1= (const float*)d_in[10];
    const float* b_gat1 = (const float*)d_in[11];
    const float* W_gat2 = (const float*)d_in[12];
    const float* We_gat2= (const float*)d_in[13];
    const float* as_gat2= (const float*)d_in[14];
    const float* ad_gat2= (const float*)d_in[15];
    const float* ae_gat2= (const float*)d_in[16];
    const float* b_gat2 = (const float*)d_in[17];
    const float* W_fc1 = (const float*)d_in[18];
    const float* b_fc1 = (const float*)d_in[19];
    const float* W_fc2 = (const float*)d_in[20];
    const float* b_fc2 = (const float*)d_in[21];
    const int* src = edge_index;
    const int* dst = edge_index + N_EDGES;

    char* w = (char*)d_ws;
    auto alloc = [&](size_t bytes) -> char* {
        char* p = w; w += (bytes + 255) & ~(size_t)255; return p;
    };
    int*   cnt      = (int*)  alloc(N_NODES * 4);
    int*   rowstart = (int*)  alloc((N_NODES + 1) * 4);
    int*   cursor   = (int*)  alloc(N_NODES * 4);
    int2*  csr_es   = (int2*) alloc((size_t)N_EDGES * 8);
    float* dinv     = (float*)alloc(N_NODES * 4);
    float* a_s      = (float*)alloc(N_NODES * 4);
    float* a_d      = (float*)alloc(N_NODES * 4);
    float* dot1     = (float*)alloc((size_t)N_EDGES * 4);
    float* dot2     = (float*)alloc((size_t)N_EDGES * 4);
    float* bufA     = (float*)alloc((size_t)N_NODES * HID * 4);
    float* bufB     = (float*)alloc((size_t)N_NODES * HID * 4);
    int*   bsum     = (int*)  alloc(4096);

    hipMemsetAsync(cnt,    0, N_NODES * 4, stream);
    hipMemsetAsync(cursor, 0, N_NODES * 4, stream);

    // CSR build (shared by all three conv layers)
    k_indeg  <<<(N_EDGES + 255) / 256, 256, 0, stream>>>(dst, cnt);
    k_scan1  <<<NB, 256, 0, stream>>>(cnt, rowstart, bsum);
    k_scan2  <<<1, 512, 0, stream>>>(bsum);
    k_scan3  <<<NB, 256, 0, stream>>>(rowstart, bsum);
    k_scatter<<<(N_EDGES + 255) / 256, 256, 0, stream>>>(src, dst, rowstart, cursor, csr_es);
    k_dinv   <<<(N_NODES + 255) / 256, 256, 0, stream>>>(cnt, dinv);

    // per-edge attention dots for both GAT layers (one streaming pass over ea)
    k_dot2<<<(N_EDGES + 255) / 256, 256, 0, stream>>>(edge_attr, We_gat1, ae_gat1,
                                                      We_gat2, ae_gat2, dot1, dot2);

    // GCN
    k_gemm_gcn<<<1024, 256, 0, stream>>>(x, W_gcn, bufB);
    k_gcn_agg <<<(N_NODES + 3) / 4, 256, 0, stream>>>(bufB, rowstart, csr_es, dinv, b_gcn, bufA);

    // GAT 1
    k_gemm_gat<<<1024, 256, 0, stream>>>(bufA, W_gat1, as_gat1, ad_gat1, bufB, a_s, a_d);
    k_gat_agg <<<(N_NODES + 3) / 4, 256, 0, stream>>>(bufB, rowstart, csr_es, dot1, a_s, a_d, b_gat1, bufA);

    // GAT 2
    k_gemm_gat<<<1024, 256, 0, stream>>>(bufA, W_gat2, as_gat2, ad_gat2, bufB, a_s, a_d);
    k_gat_agg <<<(N_NODES + 3) / 4, 256, 0, stream>>>(bufB, rowstart, csr_es, dot2, a_s, a_d, b_gat2, bufA);

    // fused pool + FCs (batch sorted -> binary search per graph, no atomics)
    k_pool_fc<<<(NGRAPH + 3) / 4, 256, 0, stream>>>(bufA, batch, W_fc1, b_fc1, W_fc2, b_fc2, (float*)d_out);
}